// Round 9
// baseline (124.920 us; speedup 1.0000x reference)
//
#include <hip/hip_runtime.h>
#include <hip/hip_bf16.h>

typedef float f32x4 __attribute__((ext_vector_type(4)));
typedef __bf16 bf16x8 __attribute__((ext_vector_type(8)));
typedef unsigned short u16x8 __attribute__((ext_vector_type(8)));
typedef unsigned short u16x4 __attribute__((ext_vector_type(4)));
typedef unsigned u32x4 __attribute__((ext_vector_type(4)));

#define NB 4
#define SL 2048
#define NH 16
#define HD 64
#define QBLK 128
#define KBLK 64
#define PAD 72
#define NT (SL / QBLK)

static __device__ __forceinline__ unsigned short f2bf(float f) {
    unsigned u = __builtin_bit_cast(unsigned, f);
    u += 0x7fffu + ((u >> 16) & 1u);
    return (unsigned short)(u >> 16);
}

static __device__ __forceinline__ unsigned pk2(float lo, float hi) {
    unsigned r;
    asm("v_cvt_pk_bf16_f32 %0, %1, %2" : "=v"(r) : "v"(lo), "v"(hi));
    return r;
}

// a' = [a.lo32 | b.lo32], b' = [a.hi32 | b.hi32]
static __device__ __forceinline__ void pl32swap(unsigned& a, unsigned& b) {
    asm("v_permlane32_swap_b32 %0, %1" : "+v"(a), "+v"(b));
}
// a' = [a.r0, b.r0, a.r2, b.r2], b' = [a.r1, b.r1, a.r3, b.r3] (16-lane rows)
static __device__ __forceinline__ void pl16swap(unsigned& a, unsigned& b) {
    asm("v_permlane16_swap_b32 %0, %1" : "+v"(a), "+v"(b));
}

// ---- prologue 1: K fp32 [b][s][h][e] -> bf16 [b][h][s][e] ----
__global__ void conv_k(const float* __restrict__ Kg, unsigned short* __restrict__ Kb) {
    const int idx = (blockIdx.x * 256 + threadIdx.x) * 4;
    const int e    = idx & 63;
    const int rest = idx >> 6;
    const int h    = rest & 15;
    const int bs   = rest >> 4;
    const int b    = bs >> 11;
    const int s    = bs & (SL - 1);
    f32x4 v = *(const f32x4*)(Kg + idx);
    u16x4 o;
    #pragma unroll
    for (int j = 0; j < 4; ++j) o[j] = f2bf(v[j]);
    *(u16x4*)(Kb + (((size_t)(b * NH + h) * SL + s) * HD + e)) = o;
}

// ---- prologue 2: V fp32 [b][s][h][d] -> bf16 transposed [b][h][d][s] ----
__global__ void conv_v(const float* __restrict__ Vg, unsigned short* __restrict__ Vtb) {
    __shared__ unsigned short T[64 * PAD];
    const int tid = threadIdx.x;
    const int id  = blockIdx.x;
    const int st  = id & 31;
    const int bh  = id >> 5;
    const int s0  = st * 64;
    {
        const int sl = tid >> 2, c = (tid & 3) * 16;
        const float* src = Vg + ((size_t)((bh >> 4) * SL + s0 + sl) * NH + (bh & 15)) * HD + c;
        u16x8 a, b2;
        #pragma unroll
        for (int j = 0; j < 8; ++j) { a[j] = f2bf(src[j]); b2[j] = f2bf(src[8 + j]); }
        *(u16x8*)&T[sl * PAD + c]     = a;
        *(u16x8*)&T[sl * PAD + c + 8] = b2;
    }
    __syncthreads();
    {
        const int d = tid >> 2, sc = (tid & 3) * 16;
        u16x8 o0, o1;
        #pragma unroll
        for (int j = 0; j < 8; ++j) { o0[j] = T[(sc + j) * PAD + d]; o1[j] = T[(sc + 8 + j) * PAD + d]; }
        unsigned short* dst = Vtb + ((size_t)bh * HD + d) * SL + s0 + sc;
        *(u16x8*)dst       = o0;
        *(u16x8*)(dst + 8) = o1;
    }
}

// ---- main: paired causal q-tiles, swapped-QK^T, MFMA l-sum, shfl max-reduce ----
__global__ __launch_bounds__(512, 4)
void fattn_kernel(const float* __restrict__ Qg, const unsigned short* __restrict__ Kb,
                  const unsigned short* __restrict__ Vtb, float* __restrict__ Og)
{
    __shared__ unsigned short Klds[KBLK * PAD];
    __shared__ unsigned short Vlds[HD * PAD];

    const int tid  = threadIdx.x;
    const int w    = tid >> 6;
    const int lane = tid & 63;
    const int g    = lane >> 4;
    const int li   = lane & 15;

    const int bh   = blockIdx.x & 63;
    const int rawp = blockIdx.x >> 6;
    const int p    = (rawp < 4) ? rawp : 11 - rawp;
    const int b    = bh >> 4;
    const int h    = bh & 15;

    const int qrow0 = p * QBLK + w * 16;
    const int qrow1 = (NT - 1 - p) * QBLK + w * 16;
    const int tmax  = 2 * (NT - 1 - p) + 1;

    const float QSCALE = 0.125f * 1.44269504088896f;  // (1/sqrt64)*log2(e)
    bf16x8 qfrag[2][2];
    #pragma unroll
    for (int fi = 0; fi < 2; ++fi) {
        const int q = (fi == 0 ? qrow0 : qrow1) + li;
        const float* qp = Qg + ((size_t)(b * SL + q) * NH + h) * HD + g * 8;
        #pragma unroll
        for (int c = 0; c < 2; ++c) {
            f32x4 a = *(const f32x4*)(qp + c * 32);
            f32x4 b2 = *(const f32x4*)(qp + c * 32 + 4);
            u16x8 t;
            #pragma unroll
            for (int j = 0; j < 4; ++j) { t[j] = f2bf(a[j] * QSCALE); t[4 + j] = f2bf(b2[j] * QSCALE); }
            qfrag[fi][c] = __builtin_bit_cast(bf16x8, t);
        }
    }

    // all-ones bf16 fragment for the MFMA l-sum trick
    u16x8 onesu;
    #pragma unroll
    for (int j = 0; j < 8; ++j) onesu[j] = 0x3F80;
    const bf16x8 vones = __builtin_bit_cast(bf16x8, onesu);

    float m_run[2] = {-1e30f, -1e30f};
    f32x4 lsum[2];
    f32x4 oacc[2][4];
    #pragma unroll
    for (int fi = 0; fi < 2; ++fi) {
        lsum[fi] = f32x4{0.f, 0.f, 0.f, 0.f};
        #pragma unroll
        for (int d = 0; d < 4; ++d) oacc[fi][d] = f32x4{0.f, 0.f, 0.f, 0.f};
    }

    const int srow = tid >> 3;
    const int scol = (tid & 7) * 8;
    const unsigned short* kbase = Kb  + (size_t)bh * SL * HD;
    const unsigned short* vbase = Vtb + (size_t)bh * HD * SL;

    u16x8 kreg = *(const u16x8*)(kbase + (size_t)srow * HD + scol);
    u16x8 vreg = *(const u16x8*)(vbase + (size_t)srow * SL + scol);

    for (int t = 0; t <= tmax; ++t) {
        const int s0 = t * KBLK;
        __syncthreads();
        *(u16x8*)&Klds[srow * PAD + scol] = kreg;
        *(u16x8*)&Vlds[srow * PAD + scol] = vreg;
        if (t < tmax) {
            const int s1 = s0 + KBLK;
            kreg = *(const u16x8*)(kbase + ((size_t)(s1 + srow)) * HD + scol);
            vreg = *(const u16x8*)(vbase + (size_t)srow * SL + s1 + scol);
        }
        __syncthreads();

        const bool act0 = (s0 <= qrow0 + 15);
        bf16x8 pfr[2][2];

        // K fragments are fi-invariant: read once per tile
        bf16x8 kfr[4][2];
        #pragma unroll
        for (int sub = 0; sub < 4; ++sub) {
            kfr[sub][0] = __builtin_bit_cast(bf16x8, *(u16x8*)&Klds[(sub * 16 + li) * PAD + g * 8]);
            kfr[sub][1] = __builtin_bit_cast(bf16x8, *(u16x8*)&Klds[(sub * 16 + li) * PAD + 32 + g * 8]);
        }

        #pragma unroll
        for (int fi = 0; fi < 2; ++fi) {
            if (fi == 0 && !act0) continue;
            const int qf = (fi == 0) ? qrow0 : qrow1;

            // S^T = K Q^T : lane holds col q=qf+li, rows s = s0+sub*16+g*4+r
            f32x4 sacc[4];
            __builtin_amdgcn_s_setprio(1);
            #pragma unroll
            for (int sub = 0; sub < 4; ++sub) {
                f32x4 c = f32x4{0.f, 0.f, 0.f, 0.f};
                c = __builtin_amdgcn_mfma_f32_16x16x32_bf16(kfr[sub][0], qfrag[fi][0], c, 0, 0, 0);
                c = __builtin_amdgcn_mfma_f32_16x16x32_bf16(kfr[sub][1], qfrag[fi][1], c, 0, 0, 0);
                sacc[sub] = c;
            }
            __builtin_amdgcn_s_setprio(0);

            // causal mask: s > q
            if (s0 + KBLK - 1 > qf) {
                const int q = qf + li;
                #pragma unroll
                for (int sub = 0; sub < 4; ++sub)
                    #pragma unroll
                    for (int r = 0; r < 4; ++r)
                        if (s0 + sub * 16 + g * 4 + r > q) sacc[sub][r] = -1e30f;
            }

            // row max: max3-shaped chain + PROVEN shfl_xor cross-lane reduce
            float t0 = fmaxf(fmaxf(sacc[0][0], sacc[0][1]), sacc[0][2]);
            float t1 = fmaxf(fmaxf(sacc[0][3], sacc[1][0]), sacc[1][1]);
            float t2 = fmaxf(fmaxf(sacc[1][2], sacc[1][3]), sacc[2][0]);
            float t3 = fmaxf(fmaxf(sacc[2][1], sacc[2][2]), sacc[2][3]);
            float t4 = fmaxf(fmaxf(sacc[3][0], sacc[3][1]), sacc[3][2]);
            float u0 = fmaxf(fmaxf(t0, t1), t2);
            float u1 = fmaxf(fmaxf(t3, t4), sacc[3][3]);
            float pmax = fmaxf(u0, u1);
            pmax = fmaxf(pmax, __shfl_xor(pmax, 16, 64));
            pmax = fmaxf(pmax, __shfl_xor(pmax, 32, 64));

            // defer-max (T13): rescale only when max grew past THR=8
            if (!__all(pmax - m_run[fi] <= 8.0f)) {
                const float mnew = fmaxf(m_run[fi], pmax);
                const float alpha = exp2f(m_run[fi] - mnew);
                m_run[fi] = mnew;
                #pragma unroll
                for (int r = 0; r < 4; ++r) lsum[fi][r] *= alpha;
                #pragma unroll
                for (int d = 0; d < 4; ++d)
                    #pragma unroll
                    for (int r = 0; r < 4; ++r) oacc[fi][d][r] *= alpha;
            }

            // P = 2^(S-m)  (row-sum comes from the MFMA ones-trick below)
            #pragma unroll
            for (int sub = 0; sub < 4; ++sub)
                #pragma unroll
                for (int r = 0; r < 4; ++r)
                    sacc[sub][r] = exp2f(sacc[sub][r] - m_run[fi]);

            // in-register P exchange: pack + permlane (no LDS)
            unsigned X00 = pk2(sacc[0][0], sacc[0][1]);
            unsigned X01 = pk2(sacc[0][2], sacc[0][3]);
            unsigned X10 = pk2(sacc[1][0], sacc[1][1]);
            unsigned X11 = pk2(sacc[1][2], sacc[1][3]);
            unsigned X20 = pk2(sacc[2][0], sacc[2][1]);
            unsigned X21 = pk2(sacc[2][2], sacc[2][3]);
            unsigned X30 = pk2(sacc[3][0], sacc[3][1]);
            unsigned X31 = pk2(sacc[3][2], sacc[3][3]);
            pl32swap(X00, X10); pl16swap(X00, X10);
            pl32swap(X01, X11); pl16swap(X01, X11);
            pl32swap(X20, X30); pl16swap(X20, X30);
            pl32swap(X21, X31); pl16swap(X21, X31);
            u32x4 w0 = {X00, X01, X10, X11};
            u32x4 w1 = {X20, X21, X30, X31};
            pfr[fi][0] = __builtin_bit_cast(bf16x8, w0);
            pfr[fi][1] = __builtin_bit_cast(bf16x8, w1);

            // l-sum on the matrix pipe: every output element = sum_s P[s][li]
            __builtin_amdgcn_s_setprio(1);
            lsum[fi] = __builtin_amdgcn_mfma_f32_16x16x32_bf16(vones, pfr[fi][0], lsum[fi], 0, 0, 0);
            lsum[fi] = __builtin_amdgcn_mfma_f32_16x16x32_bf16(vones, pfr[fi][1], lsum[fi], 0, 0, 0);
            __builtin_amdgcn_s_setprio(0);
        }

        // PV: oacc += V^T x P  (V-frags shared across both fi)
        __builtin_amdgcn_s_setprio(1);
        #pragma unroll
        for (int d = 0; d < 4; ++d) {
            bf16x8 vf0 = __builtin_bit_cast(bf16x8, *(u16x8*)&Vlds[(d * 16 + li) * PAD + g * 8]);
            bf16x8 vf1 = __builtin_bit_cast(bf16x8, *(u16x8*)&Vlds[(d * 16 + li) * PAD + 32 + g * 8]);
            #pragma unroll
            for (int fi = 0; fi < 2; ++fi) {
                if (fi == 0 && !act0) continue;
                oacc[fi][d] = __builtin_amdgcn_mfma_f32_16x16x32_bf16(vf0, pfr[fi][0], oacc[fi][d], 0, 0, 0);
                oacc[fi][d] = __builtin_amdgcn_mfma_f32_16x16x32_bf16(vf1, pfr[fi][1], oacc[fi][d], 0, 0, 0);
            }
        }
        __builtin_amdgcn_s_setprio(0);
    }

    // epilogue: lane owns q-row qf+li, cols dd = d*16 + g*4 + r
    #pragma unroll
    for (int fi = 0; fi < 2; ++fi) {
        const int qf = (fi == 0) ? qrow0 : qrow1;
        const float inv = 1.0f / lsum[fi][0];
        float* op = Og + ((size_t)(b * SL + qf + li) * NH + h) * HD + g * 4;
        #pragma unroll
        for (int d = 0; d < 4; ++d) {
            f32x4 o = oacc[fi][d];
            #pragma unroll
            for (int r = 0; r < 4; ++r) o[r] *= inv;
            *(f32x4*)(op + d * 16) = o;
        }
    }
}

extern "C" void kernel_launch(void* const* d_in, const int* in_sizes, int n_in,
                              void* d_out, int out_size, void* d_ws, size_t ws_size,
                              hipStream_t stream) {
    const float* Qg = (const float*)d_in[0];
    const float* Kg = (const float*)d_in[1];
    const float* Vg = (const float*)d_in[2];
    float* Og = (float*)d_out;

    const size_t elems = (size_t)NB * NH * SL * HD;
    if (ws_size < 2 * elems * sizeof(unsigned short)) return;
    unsigned short* Kb  = (unsigned short*)d_ws;
    unsigned short* Vtb = Kb + elems;

    hipLaunchKernelGGL(conv_k, dim3(elems / 4 / 256), dim3(256), 0, stream, Kg, Kb);
    hipLaunchKernelGGL(conv_v, dim3(NB * NH * (SL / 64)), dim3(256), 0, stream, Vg, Vtb);
    hipLaunchKernelGGL(fattn_kernel, dim3((NT / 2) * 64), dim3(512), 0, stream,
                       Qg, Kb, Vtb, Og);
}